// Round 6
// baseline (44.090 us; speedup 1.0000x reference)
//
#include <hip/hip_runtime.h>
#include <hip/hip_bf16.h>

#define B_ 8
#define C_ 64
#define O_ 64
#define H_ 128
#define W_ 128
#define HW_ (H_ * W_)

typedef __attribute__((ext_vector_type(8))) short bf16x8;
typedef __attribute__((ext_vector_type(4))) float f32x4;

__device__ __forceinline__ unsigned short f2bf(float v) {
    unsigned u = __float_as_uint(v);
    return (unsigned short)((u + 0x7FFFu + ((u >> 16) & 1u)) >> 16);
}
__device__ __forceinline__ int swz(int col) {   // 16B slot selector
    return ((col ^ (col >> 3)) & 7) << 4;
}
__device__ __forceinline__ int clampi(int v, int lo, int hi) {
    return v < lo ? lo : (v > hi ? hi : v);
}

// ---- weight prep: wfrag flat = (((t*2+ks)*4+of)*64 + lane)*8 + j ----
// o = of*16 + (lane&15), c = ks*32 + ((lane>>4)&3)*8 + j  (MFMA B-frag order)
__global__ void prep_weights(const float* __restrict__ weight,
                             unsigned short* __restrict__ wfrag) {
    int idx = blockIdx.x * 256 + threadIdx.x;
    if (idx >= 9 * 4096) return;
    int j  = idx & 7;
    int l  = (idx >> 3) & 63;
    int fi = (idx >> 9) & 3;
    int ks = (idx >> 11) & 1;
    int t  = idx >> 12;
    int o  = fi * 16 + (l & 15);
    int c  = ks * 32 + ((l >> 4) & 3) * 8 + j;
    wfrag[idx] = f2bf(weight[(o * C_ + c) * 9 + t]);
}

// One 4-row x 32-col tile's MFMA loop. SB = sim px offset (0 for A, 32 for B).
template<int SB>
__device__ __forceinline__ void compute_tile(
    const unsigned char* xs, const float (&sim)[9][4][64],
    const unsigned short* __restrict__ wfrag,
    int hr, int g, int ln, int lane, float (&acc)[2][4][4]) {
    #pragma unroll 1
    for (int kh = 0; kh < 3; ++kh) {
        #pragma unroll
        for (int kw = 0; kw < 3; ++kw) {
            const int t = kh * 3 + kw;
            bf16x8 bfr[2][4];
            #pragma unroll
            for (int ks = 0; ks < 2; ++ks)
                #pragma unroll
                for (int of = 0; of < 4; ++of)
                    bfr[ks][of] = *(const bf16x8*)(
                        wfrag + (((t * 2 + ks) * 4 + of) * 64 + lane) * 8);

            #pragma unroll
            for (int pf = 0; pf < 2; ++pf) {
                int col = pf * 16 + ln + kw;            // 0..33
                const unsigned char* rowp = xs + ((hr + kh) * 34 + col) * 128;
                bf16x8 af0 = *(const bf16x8*)(rowp + ((16 * g) ^ swz(col)));
                bf16x8 af1 = *(const bf16x8*)(rowp + ((64 + 16 * g) ^ swz(col)));

                f32x4 prt[4] = {};
                #pragma unroll
                for (int of = 0; of < 4; ++of)
                    prt[of] = __builtin_amdgcn_mfma_f32_16x16x32_bf16(
                        af0, bfr[0][of], prt[of], 0, 0, 0);
                #pragma unroll
                for (int of = 0; of < 4; ++of)
                    prt[of] = __builtin_amdgcn_mfma_f32_16x16x32_bf16(
                        af1, bfr[1][of], prt[of], 0, 0, 0);

                f32x4 sv = *(const f32x4*)&sim[t][hr][SB + pf * 16 + g * 4];
                #pragma unroll
                for (int of = 0; of < 4; ++of)
                    #pragma unroll
                    for (int r = 0; r < 4; ++r)
                        acc[pf][of][r] = fmaf(sv[r], prt[of][r], acc[pf][of][r]);
            }
        }
    }
}

// Block: (b, 4-row group h0, 64-col pair 'base'). Two 32-col tiles A/B,
// register-pipelined: B's global loads fly under A's compute.
// xs: bf16 c-innermost: byte(rc = r*34+col, c) = rc*128 + ((2c) ^ swz(col))
__global__ __launch_bounds__(256, 2)
void depthconv_mfma8(const float* __restrict__ x,
                     const float* __restrict__ depth,
                     const unsigned short* __restrict__ wfrag,
                     const float* __restrict__ bias,
                     float* __restrict__ out) {
    __shared__ __align__(16) unsigned char xs[204 * 128];   // 26112 B
    __shared__ __align__(16) float sim[9][4][64];           // 9216 B
    __shared__ __align__(16) float dt[6][68];               // 1632 B

    const int tid  = threadIdx.x;
    const int blk  = blockIdx.x;          // 512 blocks
    const int wp   = blk & 1;
    const int rg   = blk >> 1;
    const int h0   = (rg & 31) * 4;
    const int b    = rg >> 5;
    const int base = wp * 64;

    // ---- depth tile: rows h0-1..h0+4, cols base-1..base+64 ----
    for (int i = tid; i < 396; i += 256) {
        int r = i / 66, col = i - r * 66;
        int gh = h0 - 1 + r, gw = base - 1 + col;
        bool ok = ((unsigned)gh < (unsigned)H_) && ((unsigned)gw < (unsigned)W_);
        float v = depth[(b * H_ + clampi(gh, 0, H_ - 1)) * W_ + clampi(gw, 0, W_ - 1)];
        dt[r][col] = ok ? v : 0.f;
    }
    __syncthreads();

    const int q  = tid & 7;       // float4 slot (cols w0 + q*4)
    const int pc = tid >> 3;      // channel pair 0..31

    // ---- issue tile-A loads ----
    float4 xa[6], xb[6];
    #pragma unroll
    for (int r = 0; r < 6; ++r) {
        int ghc = clampi(h0 - 1 + r, 0, H_ - 1);
        const float* p = &x[((b * C_ + 2 * pc) * H_ + ghc) * W_ + base + q * 4];
        xa[r] = *(const float4*)p;
        xb[r] = *(const float4*)(p + HW_);
    }
    float ha[2][2];
    #pragma unroll
    for (int k = 0; k < 2; ++k) {
        int i = tid + 256 * k;                 // side x pair x r = 384 items
        if (i < 384) {
            int side = i & 1, pair = (i >> 1) & 31, r = i >> 6;
            int gh = h0 - 1 + r;
            int gw = side ? base + 32 : base - 1;
            bool ok = ((unsigned)gh < (unsigned)H_) && ((unsigned)gw < (unsigned)W_);
            const float* p = &x[((b * C_ + 2 * pair) * H_ + clampi(gh, 0, H_ - 1)) * W_
                                + clampi(gw, 0, W_ - 1)];
            float v0 = p[0], v1 = p[HW_];
            ha[k][0] = ok ? v0 : 0.f;
            ha[k][1] = ok ? v1 : 0.f;
        }
    }

    // ---- sim (full 64-px width) while A-loads fly ----
    {
        int sr = tid >> 6, px = tid & 63;
        #pragma unroll
        for (int t = 0; t < 9; ++t) {
            const int kh = t / 3, kw = t % 3;
            sim[t][sr][px] = expf(-fabsf(dt[sr + kh][px + kw] - dt[sr + 1][px + 1]));
        }
    }

    // ---- cvt + LDS-write tile A ----
    #pragma unroll
    for (int r = 0; r < 6; ++r) {
        int gh = h0 - 1 + r;
        bool okh = (unsigned)gh < (unsigned)H_;
        float va[4] = {xa[r].x, xa[r].y, xa[r].z, xa[r].w};
        float vb[4] = {xb[r].x, xb[r].y, xb[r].z, xb[r].w};
        #pragma unroll
        for (int m = 0; m < 4; ++m) {
            int col = 1 + q * 4 + m;
            float2 pr;
            pr.x = okh ? va[m] : 0.f;
            pr.y = okh ? vb[m] : 0.f;
            __hip_bfloat162 bv = __float22bfloat162_rn(pr);
            *(__hip_bfloat162*)(xs + (r * 34 + col) * 128 + ((4 * pc) ^ swz(col))) = bv;
        }
    }
    #pragma unroll
    for (int k = 0; k < 2; ++k) {
        int i = tid + 256 * k;
        if (i < 384) {
            int side = i & 1, pair = (i >> 1) & 31, r = i >> 6;
            int col = side ? 33 : 0;
            float2 pr; pr.x = ha[k][0]; pr.y = ha[k][1];
            __hip_bfloat162 bv = __float22bfloat162_rn(pr);
            *(__hip_bfloat162*)(xs + (r * 34 + col) * 128 + ((4 * pair) ^ swz(col))) = bv;
        }
    }
    __syncthreads();

    // ---- issue tile-B loads (pinned above compute A) ----
    float4 ya[6], yb[6];
    #pragma unroll
    for (int r = 0; r < 6; ++r) {
        int ghc = clampi(h0 - 1 + r, 0, H_ - 1);
        const float* p = &x[((b * C_ + 2 * pc) * H_ + ghc) * W_ + base + 32 + q * 4];
        ya[r] = *(const float4*)p;
        yb[r] = *(const float4*)(p + HW_);
    }
    float hb[2][2];
    #pragma unroll
    for (int k = 0; k < 2; ++k) {
        int i = tid + 256 * k;
        if (i < 384) {
            int side = i & 1, pair = (i >> 1) & 31, r = i >> 6;
            int gh = h0 - 1 + r;
            int gw = side ? base + 64 : base + 31;
            bool ok = ((unsigned)gh < (unsigned)H_) && ((unsigned)gw < (unsigned)W_);
            const float* p = &x[((b * C_ + 2 * pair) * H_ + clampi(gh, 0, H_ - 1)) * W_
                                + clampi(gw, 0, W_ - 1)];
            float v0 = p[0], v1 = p[HW_];
            hb[k][0] = ok ? v0 : 0.f;
            hb[k][1] = ok ? v1 : 0.f;
        }
    }
    __builtin_amdgcn_sched_barrier(0);

    // ---- compute tile A (B's loads in flight underneath) ----
    const int lane = tid & 63;
    const int hr   = tid >> 6;
    const int g    = lane >> 4;
    const int ln   = lane & 15;

    float accA[2][4][4];
    #pragma unroll
    for (int of = 0; of < 4; ++of) {
        float bv = bias[of * 16 + ln];
        #pragma unroll
        for (int pf = 0; pf < 2; ++pf)
            #pragma unroll
            for (int r = 0; r < 4; ++r)
                accA[pf][of][r] = bv;
    }
    compute_tile<0>(xs, sim, wfrag, hr, g, ln, lane, accA);
    __syncthreads();                      // all waves done reading xs (tile A)

    // ---- cvt + LDS-write tile B ----
    #pragma unroll
    for (int r = 0; r < 6; ++r) {
        int gh = h0 - 1 + r;
        bool okh = (unsigned)gh < (unsigned)H_;
        float va[4] = {ya[r].x, ya[r].y, ya[r].z, ya[r].w};
        float vb[4] = {yb[r].x, yb[r].y, yb[r].z, yb[r].w};
        #pragma unroll
        for (int m = 0; m < 4; ++m) {
            int col = 1 + q * 4 + m;
            float2 pr;
            pr.x = okh ? va[m] : 0.f;
            pr.y = okh ? vb[m] : 0.f;
            __hip_bfloat162 bv = __float22bfloat162_rn(pr);
            *(__hip_bfloat162*)(xs + (r * 34 + col) * 128 + ((4 * pc) ^ swz(col))) = bv;
        }
    }
    #pragma unroll
    for (int k = 0; k < 2; ++k) {
        int i = tid + 256 * k;
        if (i < 384) {
            int side = i & 1, pair = (i >> 1) & 31, r = i >> 6;
            int col = side ? 33 : 0;
            float2 pr; pr.x = hb[k][0]; pr.y = hb[k][1];
            __hip_bfloat162 bv = __float22bfloat162_rn(pr);
            *(__hip_bfloat162*)(xs + (r * 34 + col) * 128 + ((4 * pair) ^ swz(col))) = bv;
        }
    }
    __syncthreads();

    // ---- compute tile B ----
    float accB[2][4][4];
    #pragma unroll
    for (int of = 0; of < 4; ++of) {
        float bv = bias[of * 16 + ln];
        #pragma unroll
        for (int pf = 0; pf < 2; ++pf)
            #pragma unroll
            for (int r = 0; r < 4; ++r)
                accB[pf][of][r] = bv;
    }
    compute_tile<32>(xs, sim, wfrag, hr, g, ln, lane, accB);

    // ---- stores: per o-row 4 back-to-back 64B spans = full 256B lines ----
    const int h = h0 + hr;
    #pragma unroll
    for (int of = 0; of < 4; ++of) {
        int o = of * 16 + ln;
        float* dst = out + (((size_t)(b * O_ + o) * H_ + h) * W_) + base;
        #pragma unroll
        for (int pf = 0; pf < 2; ++pf) {
            f32x4 v = { accA[pf][of][0], accA[pf][of][1],
                        accA[pf][of][2], accA[pf][of][3] };
            *(f32x4*)(dst + pf * 16 + g * 4) = v;
        }
        #pragma unroll
        for (int pf = 0; pf < 2; ++pf) {
            f32x4 v = { accB[pf][of][0], accB[pf][of][1],
                        accB[pf][of][2], accB[pf][of][3] };
            *(f32x4*)(dst + 32 + pf * 16 + g * 4) = v;
        }
    }
}

extern "C" void kernel_launch(void* const* d_in, const int* in_sizes, int n_in,
                              void* d_out, int out_size, void* d_ws, size_t ws_size,
                              hipStream_t stream) {
    const float* x      = (const float*)d_in[0];
    const float* depth  = (const float*)d_in[1];
    const float* weight = (const float*)d_in[2];
    const float* bias   = (const float*)d_in[3];
    float* out          = (float*)d_out;
    unsigned short* wfrag = (unsigned short*)d_ws;   // 73,728 B

    prep_weights<<<dim3(144), dim3(256), 0, stream>>>(weight, wfrag);
    depthconv_mfma8<<<dim3(512), dim3(256), 0, stream>>>(
        x, depth, wfrag, bias, out);
}

// Round 7
// 43.173 us; speedup vs baseline: 1.0213x; 1.0213x over previous
//
#include <hip/hip_runtime.h>
#include <hip/hip_bf16.h>

#define B_ 8
#define C_ 64
#define O_ 64
#define H_ 128
#define W_ 128
#define HW_ (H_ * W_)

typedef __attribute__((ext_vector_type(8))) short bf16x8;
typedef __attribute__((ext_vector_type(4))) float f32x4;

__device__ __forceinline__ unsigned short f2bf(float v) {
    unsigned u = __float_as_uint(v);
    return (unsigned short)((u + 0x7FFFu + ((u >> 16) & 1u)) >> 16);
}
__device__ __forceinline__ int swz(int col) {   // 16B slot selector
    return ((col ^ (col >> 3)) & 7) << 4;
}
__device__ __forceinline__ int clampi(int v, int lo, int hi) {
    return v < lo ? lo : (v > hi ? hi : v);
}

// ---- weight prep: wfrag flat = (((t*2+ks)*4+fi)*64 + lane)*8 + j ----
// o = fi*16 + (lane&15), c = ks*32 + ((lane>>4)&3)*8 + j  (MFMA B-frag order)
__global__ void prep_weights(const float* __restrict__ weight,
                             unsigned short* __restrict__ wfrag) {
    int idx = blockIdx.x * 256 + threadIdx.x;
    if (idx >= 9 * 4096) return;
    int j  = idx & 7;
    int l  = (idx >> 3) & 63;
    int fi = (idx >> 9) & 3;
    int ks = (idx >> 11) & 1;
    int t  = idx >> 12;
    int o  = fi * 16 + (l & 15);
    int c  = ks * 32 + ((l >> 4) & 3) * 8 + j;
    wfrag[idx] = f2bf(weight[(o * C_ + c) * 9 + t]);
}

// Block: (b, 4-row group h0, w-half w0). 512 threads = 8 waves.
// Wave w: hr = w>>1 (output row), oh = w&1 (32-o half). Same tile/layout as
// the 36.6us round-5 kernel; 2x waves halve per-wave work -> 16 waves/CU.
// xs: bf16 c-innermost: byte(rc = r*66+col, c) = rc*128 + ((2c) ^ swz(col))
__global__ __launch_bounds__(512, 4)
void depthconv_mfma10(const float* __restrict__ x,
                      const float* __restrict__ depth,
                      const unsigned short* __restrict__ wfrag,
                      const float* __restrict__ bias,
                      float* __restrict__ out) {
    __shared__ __align__(16) unsigned char xs[396 * 128];   // 50688 B
    __shared__ __align__(16) float sim[9][4][64];           // 9216 B
    __shared__ __align__(16) float dt[6][68];               // 1632 B

    const int tid = threadIdx.x;
    const int blk = blockIdx.x;
    const int b   = blk >> 6;            // 64 blocks per batch
    const int rem = blk & 63;
    const int h0  = (rem >> 1) * 4;
    const int w0  = (rem & 1) * 64;

    // ---- stage depth tile (6 x 66) ----
    if (tid < 396) {
        int r = tid / 66, col = tid - r * 66;
        int gh = h0 - 1 + r, gw = w0 - 1 + col;
        bool ok = ((unsigned)gh < (unsigned)H_) && ((unsigned)gw < (unsigned)W_);
        float v = depth[(b * H_ + clampi(gh, 0, H_ - 1)) * W_ + clampi(gw, 0, W_ - 1)];
        dt[r][col] = ok ? v : 0.f;
    }
    __syncthreads();

    // ---- issue x loads: q = f4 slot, pc = channel pair 0..31, 6 rows ----
    const int q  = tid & 15;
    const int pc = tid >> 4;      // 0..31
    float4 xa[6], xb[6];
    #pragma unroll
    for (int r = 0; r < 6; ++r) {
        int ghc = clampi(h0 - 1 + r, 0, H_ - 1);
        const float* p = &x[((b * C_ + 2 * pc) * H_ + ghc) * W_ + w0 + q * 4];
        xa[r] = *(const float4*)p;
        xb[r] = *(const float4*)(p + HW_);
    }
    // halo cols (col 0 / 65): 2 sides x 32 pairs x 6 rows = 384 items
    float hl0 = 0.f, hl1 = 0.f;
    int hside = 0, hpair = 0, hrr = 0;
    if (tid < 384) {
        hside = tid & 1; hpair = (tid >> 1) & 31; hrr = tid >> 6;
        int gh = h0 - 1 + hrr;
        int gw = hside ? (w0 + 64) : (w0 - 1);
        bool ok = ((unsigned)gh < (unsigned)H_) && ((unsigned)gw < (unsigned)W_);
        const float* p = &x[((b * C_ + 2 * hpair) * H_ + clampi(gh, 0, H_ - 1)) * W_
                            + clampi(gw, 0, W_ - 1)];
        float v0 = p[0], v1 = p[HW_];
        hl0 = ok ? v0 : 0.f;
        hl1 = ok ? v1 : 0.f;
    }

    // ---- sim[t][hr][px] while x loads are in flight ----
    for (int i = tid; i < 2304; i += 512) {
        int t = i >> 8, sr = (i >> 6) & 3, px = i & 63;
        int kh = t / 3, kw = t - kh * 3;
        sim[t][sr][px] = expf(-fabsf(dt[sr + kh][px + kw] - dt[sr + 1][px + 1]));
    }

    // ---- cvt_pk + LDS write x ----
    #pragma unroll
    for (int r = 0; r < 6; ++r) {
        int gh = h0 - 1 + r;
        bool okh = (unsigned)gh < (unsigned)H_;
        float va[4] = {xa[r].x, xa[r].y, xa[r].z, xa[r].w};
        float vb[4] = {xb[r].x, xb[r].y, xb[r].z, xb[r].w};
        #pragma unroll
        for (int m = 0; m < 4; ++m) {
            int col = 1 + q * 4 + m;
            float2 pr;
            pr.x = okh ? va[m] : 0.f;
            pr.y = okh ? vb[m] : 0.f;
            __hip_bfloat162 bv = __float22bfloat162_rn(pr);
            *(__hip_bfloat162*)(xs + (r * 66 + col) * 128 + ((4 * pc) ^ swz(col))) = bv;
        }
    }
    if (tid < 384) {
        int col = hside ? 65 : 0;
        float2 pr; pr.x = hl0; pr.y = hl1;
        __hip_bfloat162 bv = __float22bfloat162_rn(pr);
        *(__hip_bfloat162*)(xs + (hrr * 66 + col) * 128 + ((4 * hpair) ^ swz(col))) = bv;
    }
    __syncthreads();

    // ---- main loop: barrier-free; wave = (output row hr, o-half oh) ----
    const int lane = tid & 63;
    const int wv   = tid >> 6;          // 0..7
    const int hr   = wv >> 1;
    const int oh   = wv & 1;
    const int g    = lane >> 4;
    const int ln   = lane & 15;

    float acc[4][2][4];                 // [pf][of][r]
    #pragma unroll
    for (int of = 0; of < 2; ++of) {
        float bv = bias[(oh * 2 + of) * 16 + ln];
        #pragma unroll
        for (int pf = 0; pf < 4; ++pf)
            #pragma unroll
            for (int r = 0; r < 4; ++r)
                acc[pf][of][r] = bv;
    }

    #pragma unroll 1
    for (int kh = 0; kh < 3; ++kh) {
        #pragma unroll
        for (int kw = 0; kw < 3; ++kw) {
            const int t = kh * 3 + kw;
            bf16x8 bfr[2][2];           // [ks][of]
            #pragma unroll
            for (int ks = 0; ks < 2; ++ks)
                #pragma unroll
                for (int of = 0; of < 2; ++of) {
                    int fi = oh * 2 + of;
                    bfr[ks][of] = *(const bf16x8*)(
                        wfrag + (((t * 2 + ks) * 4 + fi) * 64 + lane) * 8);
                }

            #pragma unroll
            for (int pf = 0; pf < 4; ++pf) {
                int col = pf * 16 + ln + kw;
                const unsigned char* rowp = xs + ((hr + kh) * 66 + col) * 128;
                bf16x8 af0 = *(const bf16x8*)(rowp + ((16 * g) ^ swz(col)));
                bf16x8 af1 = *(const bf16x8*)(rowp + ((64 + 16 * g) ^ swz(col)));

                f32x4 prt[2] = {};
                #pragma unroll
                for (int of = 0; of < 2; ++of)
                    prt[of] = __builtin_amdgcn_mfma_f32_16x16x32_bf16(
                        af0, bfr[0][of], prt[of], 0, 0, 0);
                #pragma unroll
                for (int of = 0; of < 2; ++of)
                    prt[of] = __builtin_amdgcn_mfma_f32_16x16x32_bf16(
                        af1, bfr[1][of], prt[of], 0, 0, 0);

                f32x4 sv = *(const f32x4*)&sim[t][hr][pf * 16 + g * 4];
                #pragma unroll
                for (int of = 0; of < 2; ++of)
                    #pragma unroll
                    for (int r = 0; r < 4; ++r)
                        acc[pf][of][r] = fmaf(sv[r], prt[of][r], acc[pf][of][r]);
            }
        }
    }

    // ---- direct stores (round-6-verified clean pattern) ----
    const int h = h0 + hr;
    #pragma unroll
    for (int of = 0; of < 2; ++of) {
        int o = (oh * 2 + of) * 16 + ln;
        float* dst = out + (((size_t)(b * O_ + o) * H_ + h) * W_) + w0;
        #pragma unroll
        for (int pf = 0; pf < 4; ++pf) {
            f32x4 v = { acc[pf][of][0], acc[pf][of][1],
                        acc[pf][of][2], acc[pf][of][3] };
            *(f32x4*)(dst + pf * 16 + g * 4) = v;
        }
    }
}

extern "C" void kernel_launch(void* const* d_in, const int* in_sizes, int n_in,
                              void* d_out, int out_size, void* d_ws, size_t ws_size,
                              hipStream_t stream) {
    const float* x      = (const float*)d_in[0];
    const float* depth  = (const float*)d_in[1];
    const float* weight = (const float*)d_in[2];
    const float* bias   = (const float*)d_in[3];
    float* out          = (float*)d_out;
    unsigned short* wfrag = (unsigned short*)d_ws;   // 73,728 B

    prep_weights<<<dim3(144), dim3(256), 0, stream>>>(weight, wfrag);
    depthconv_mfma10<<<dim3(512), dim3(512), 0, stream>>>(
        x, depth, wfrag, bias, out);
}